// Round 7
// baseline (199.453 us; speedup 1.0000x reference)
//
#include <hip/hip_runtime.h>
#include <stdint.h>

typedef unsigned short ushortT;

#define NROWS 131072
#define DIM 64
#define KCODES 1024
// 5 segments (xplane,eplane) = (0,0),(0,1),(0,2),(1,0),(2,0); x1e1 dropped (~4e-6).
// 6 DISTINCT planes each side: A = {x0d0,x0d1,x1d0,x1d1,x2d0,x2d1},
// B = {e0d0,e0d1,e1d0,e1d1,e2d0,e2d1}. Dedup'd 6-load schedule verified
// R6 (absmax 1.953125e-3, WRITE clean-ish, dur 121us == R13).
// R20 OCCUPANCY LESSON (R6): cutting B traffic 40% changed NOTHING ->
// not L2-BW-bound. Invariant: 2 waves/SIMD (unified VGPR ~148 > 128
// boundary, m69: waves/CU halves at 128). Both waves stall together on
// per-wave serial exposures -> matrix pipe idle 70%. Fix: 8-wave blocks,
// wave = 32 rows x 64 codes -> acc[2][4]+a[2][2]+b[2][4] = 72 operand regs,
// ~115 total < 128 -> 4 waves/SIMD.
#define NPL 6               // distinct planes per side
#define MT 64               // rows per block (512 threads, 8 waves)
#define NTC 256             // codes per code-iter (4 code-groups x 64)
#define CI (KCODES / NTC)   // 4 code iters
#define KCSTEP (4 * KCODES * 8)  // ushort per B plane = 32768 (64KB)
#define ASTEP (4 * MT * 8)       // ushort per A plane = 2048 (4KB)

typedef float f32x4 __attribute__((ext_vector_type(4)));
typedef short bf16x8 __attribute__((ext_vector_type(8)));

__device__ __forceinline__ ushortT f2bf(float f) {
  union { float f; uint32_t u; } v; v.f = f;
  return (ushortT)((v.u + 0x7FFFu + ((v.u >> 16) & 1u)) >> 16);  // RNE
}
__device__ __forceinline__ float bf2f(ushortT b) {
  union { float f; uint32_t u; } v; v.u = ((uint32_t)b) << 16;
  return v.f;
}

// Output-major prep (verified R3-R6): flat o = p*32768 + q*8192 + code*8+j;
// thread does 4 consecutive o (one uint2 store, coalesced). plane p: e-level
// ep = p>>1, d-half = p&1. h2[code] = 0.5*||e||^2 fp32 by blocks 0..3.
__global__ __launch_bounds__(256) void vq_prep(const float* __restrict__ emb,
                                               ushortT* __restrict__ Bg,
                                               float* __restrict__ h2) {
  const int o4 = (blockIdx.x * 256 + threadIdx.x) * 4;
  const int j0 = o4 & 7;                  // 0 or 4
  const int code = (o4 >> 3) & (KCODES - 1);
  const int q = (o4 >> 13) & 3;
  const int p = o4 >> 15;                 // 0..5 (block-uniform)
  const int ep = p >> 1;
  const int d0 = (p & 1) * 32 + q * 8 + j0;

  ushortT outv[4];
#pragma unroll
  for (int t = 0; t < 4; ++t) {
    float e = emb[(d0 + t) * KCODES + code];
    ushortT p0 = f2bf(e);
    ushortT pv = p0;
    if (ep == 1) {
      float r1 = e - bf2f(p0);            // exact (Sterbenz)
      pv = f2bf(r1);
    } else if (ep == 2) {
      float r1 = e - bf2f(p0);
      ushortT p1 = f2bf(r1);
      float r2 = r1 - bf2f(p1);           // exact
      pv = f2bf(r2);
    }
    outv[t] = pv;
  }
  *(uint2*)(&Bg[o4]) = *(const uint2*)(&outv[0]);

  if (blockIdx.x < 4) {
    const int c2 = blockIdx.x * 256 + threadIdx.x;
    float s = 0.f;
#pragma unroll
    for (int d = 0; d < DIM; ++d) {
      float e = emb[d * KCODES + c2];
      s = fmaf(e, e, s);
    }
    h2[c2] = 0.5f * s;
  }
}

// R20: 512 thr = 8 waves; rg = wave>>2 (row half: rows rg*32..rg*32+31),
// wg = wave&3 (code group: codes wg*64..+63). R19's verified g-loop schedule
// (5 iters x 2 clusters, b-reloads at g=2,3) and accumulation order kept
// identical per (row,code) -> absmax must stay 1.953125e-3.
__global__ __launch_bounds__(512, 4) void vq_main(const float* __restrict__ x,
                                                  const ushortT* __restrict__ Bg,
                                                  const float* __restrict__ h2,
                                                  const float* __restrict__ emb,
                                                  float* __restrict__ out) {
  __shared__ ushortT A_lds[NPL * ASTEP];  // 24 KB  [plane][quad][row][8]
  __shared__ float bvs[8][MT];
  __shared__ int bis[8][MT];
  __shared__ int widx_s[MT];

  const int tid = threadIdx.x;
  const int wave = tid >> 6, lane = tid & 63, quad = lane >> 4, lq = lane & 15;
  const int rg = wave >> 2, wg = wave & 3;
  const size_t rowbase = (size_t)blockIdx.x * MT;

  const ushortT* bci = Bg + ((size_t)(quad * KCODES + wg * 64 + lq)) * 8;
  // A base for this wave's row half: rows rg*32 + i*16 + lq (i = 0,1)
  const ushortT* abw = &A_lds[quad * (MT * 8) + (rg * 32 + lq) * 8];

  // ---- stage A: x rows -> bf16 planes, frag-major, dedup'd (6 planes) ----
  // 512 threads: row = tid>>3 (0-63), dg = (tid&7)*8 -> one k-quad (8 d's).
  {
    const int row = tid >> 3, dg = (tid & 7) << 3;
    const float4* xr = (const float4*)(x + (rowbase + row) * DIM + dg);
    float v[8];
#pragma unroll
    for (int i = 0; i < 2; ++i) {
      float4 t = xr[i];
      v[4 * i] = t.x; v[4 * i + 1] = t.y; v[4 * i + 2] = t.z; v[4 * i + 3] = t.w;
    }
    ushortT pl[3][8];
#pragma unroll
    for (int i = 0; i < 8; ++i) {
      ushortT a0 = f2bf(v[i]); float r1 = v[i] - bf2f(a0);
      ushortT a1 = f2bf(r1);   float r2 = r1 - bf2f(a1);
      pl[0][i] = a0; pl[1][i] = a1; pl[2][i] = f2bf(r2);
    }
    const int q0 = (dg & 31) >> 3;         // k-quad 0..3
    const int dh = dg >> 5;                // d-half
#pragma unroll
    for (int xp = 0; xp < 3; ++xp) {
      int pa = xp * 2 + dh;
      *(uint4*)&A_lds[pa * ASTEP + q0 * (MT * 8) + row * 8] = *(uint4*)&pl[xp][0];
    }
  }
  __syncthreads();  // A_lds ready; only block-wide barrier before epilogue

  float bestv[2][4];
  int besti[2][4];
#pragma unroll
  for (int i = 0; i < 2; ++i)
#pragma unroll
    for (int r = 0; r < 4; ++r) { bestv[i][r] = 3.4e38f; besti[i][r] = 0; }

#pragma unroll 1
  for (int ci = 0; ci < CI; ++ci) {
    const int codeBase = ci * NTC;
    const ushortT* bcur = bci + (size_t)codeBase * 8;

    bf16x8 a[2][2], b[2][4];
    // preload: b0<-p0 (e0d0), b1<-p1 (e0d1), a[0]<-A plane 0 (x0d0)
#pragma unroll
    for (int j = 0; j < 4; ++j) b[0][j] = *(const bf16x8*)(bcur + j * 128);
#pragma unroll
    for (int j = 0; j < 4; ++j) b[1][j] = *(const bf16x8*)(bcur + KCSTEP + j * 128);
#pragma unroll
    for (int i = 0; i < 2; ++i) a[0][i] = *(const bf16x8*)(abw + i * 128);

    f32x4 acc[2][4];
#pragma unroll
    for (int i = 0; i < 2; ++i)
#pragma unroll
      for (int j = 0; j < 4; ++j) acc[i][j] = (f32x4){0.f, 0.f, 0.f, 0.f};

#pragma unroll 1
    for (int g = 0; g < 5; ++g) {
      // A planes: cluster 2g uses {0,2,4,0,0}[g], 2g+1 uses {1,3,5,1,1}[g]
      const int pa1 = (g < 3) ? (2 * g + 1) : 1;   // prefetched for t1
      const int pa0n = (g < 2) ? (2 * g + 2) : 0;  // prefetched for next g's t0
      // --- t0 (cluster 2g): prefetch a[1] BEFORE MFMAs ---
#pragma unroll
      for (int i = 0; i < 2; ++i)
        a[1][i] = *(const bf16x8*)(abw + (size_t)pa1 * ASTEP + i * 128);
#pragma unroll
      for (int i = 0; i < 2; ++i)
#pragma unroll
        for (int j = 0; j < 4; ++j)
          acc[i][j] = __builtin_amdgcn_mfma_f32_16x16x32_bf16(a[0][i], b[0][j], acc[i][j], 0, 0, 0);
      if (g == 2 || g == 3) {  // uniform branch; reload after last use
        const size_t pb0 = (g == 2) ? 2 : 4;
#pragma unroll
        for (int j = 0; j < 4; ++j)
          b[0][j] = *(const bf16x8*)(bcur + pb0 * KCSTEP + j * 128);
      }
      // --- t1 (cluster 2g+1): prefetch a[0] for next g BEFORE MFMAs ---
#pragma unroll
      for (int i = 0; i < 2; ++i)
        a[0][i] = *(const bf16x8*)(abw + (size_t)pa0n * ASTEP + i * 128);
#pragma unroll
      for (int i = 0; i < 2; ++i)
#pragma unroll
        for (int j = 0; j < 4; ++j)
          acc[i][j] = __builtin_amdgcn_mfma_f32_16x16x32_bf16(a[1][i], b[1][j], acc[i][j], 0, 0, 0);
      if (g == 2 || g == 3) {
        const size_t pb1 = (g == 2) ? 3 : 5;
#pragma unroll
        for (int j = 0; j < 4; ++j)
          b[1][j] = *(const bf16x8*)(bcur + pb1 * KCSTEP + j * 128);
      }
    }

    // epilogue: val = 0.5||e||^2 - f.e ; merge into per-row running best
    float h2v[4];
#pragma unroll
    for (int j = 0; j < 4; ++j) h2v[j] = h2[codeBase + wg * 64 + j * 16 + lq];
#pragma unroll
    for (int i = 0; i < 2; ++i)
#pragma unroll
      for (int j = 0; j < 4; ++j) {
        const int idx = codeBase + wg * 64 + j * 16 + lq;
#pragma unroll
        for (int r = 0; r < 4; ++r) {
          float val = h2v[j] - acc[i][j][r];
          if (val < bestv[i][r]) { bestv[i][r] = val; besti[i][r] = idx; }  // idx ascending in (ci,j): strict < keeps lowest
        }
      }
  }

  // reduce across the 16 lanes sharing a quad (lane bits 0-3), lexicographic (val, idx)
#pragma unroll
  for (int m = 1; m < 16; m <<= 1) {
#pragma unroll
    for (int i = 0; i < 2; ++i)
#pragma unroll
      for (int r = 0; r < 4; ++r) {
        float ov = __shfl_xor(bestv[i][r], m, 64);
        int oi = __shfl_xor(besti[i][r], m, 64);
        if (ov < bestv[i][r] || (ov == bestv[i][r] && oi < besti[i][r])) {
          bestv[i][r] = ov; besti[i][r] = oi;
        }
      }
  }
  if (lq == 0) {
#pragma unroll
    for (int i = 0; i < 2; ++i)
#pragma unroll
      for (int r = 0; r < 4; ++r) {
        int row = rg * 32 + i * 16 + quad * 4 + r;  // rows this wave owns
        bvs[wave][row] = bestv[i][r];
        bis[wave][row] = besti[i][r];
      }
  }
  __syncthreads();
  if (tid < MT) {
    // candidates for row R: waves (R>>5)*4 + {0..3} (4 code groups, same rg)
    const int w0 = (tid >> 5) * 4;
    float bv = bvs[w0][tid]; int bi = bis[w0][tid];
#pragma unroll
    for (int w = 1; w < 4; ++w) {
      float ov = bvs[w0 + w][tid]; int oi = bis[w0 + w][tid];
      if (ov < bv || (ov == bv && oi < bi)) { bv = ov; bi = oi; }
    }
    widx_s[tid] = bi;
  }
  __syncthreads();
  // cooperative gather: thread handles row=tid>>3, 8 d's; emb is L2-resident
  {
    const int row = tid >> 3, dg = (tid & 7) << 3;
    const int wi = widx_s[row];
    float4* o = (float4*)(out + (rowbase + row) * DIM + dg);
#pragma unroll
    for (int i = 0; i < 2; ++i) {
      float4 t;
      t.x = emb[(dg + 4 * i + 0) * KCODES + wi];
      t.y = emb[(dg + 4 * i + 1) * KCODES + wi];
      t.z = emb[(dg + 4 * i + 2) * KCODES + wi];
      t.w = emb[(dg + 4 * i + 3) * KCODES + wi];
      o[i] = t;
    }
  }
}

extern "C" void kernel_launch(void* const* d_in, const int* in_sizes, int n_in,
                              void* d_out, int out_size, void* d_ws, size_t ws_size,
                              hipStream_t stream) {
  const float* x = (const float*)d_in[0];
  const float* emb = (const float*)d_in[1];
  float* out = (float*)d_out;

  ushortT* Bg = (ushortT*)d_ws;               // 6*32768 ushort = 384 KB
  float* h2 = (float*)(Bg + NPL * (size_t)KCSTEP);  // 4 KB

  vq_prep<<<(NPL * KCSTEP) / (4 * 256), 256, 0, stream>>>(emb, Bg, h2);
  vq_main<<<NROWS / MT, 512, 0, stream>>>(x, Bg, h2, emb, out);
}